// Round 5
// baseline (315.661 us; speedup 1.0000x reference)
//
#include <hip/hip_runtime.h>
#include <hip/hip_bf16.h>

// SwiGLU MLP: out = (silu(x@wg^T * S) * (x@wu^T * S)) @ wd^T * S,  S = 1/127
// Round 5: deepen the 8-phase pipeline to a FULL TILE of slack.
// New stage ledger (tile T, buf c=T&1): all 4 halves of T+2 staged late in
// tile T (ph3: B-halves, ph4: A-halves) into buf c regions that are dead by
// then (B fully read after ph2, A after ph3). vmcnt(8) once per tile at ph4:
// outstanding = 8(T+1, issued a full tile ago) + 8(T+2, just issued) -> waits
// only T+1 => every load has >= 4 phases (~1200+ cy) before its deadline,
// covering the ~900 cy HBM latency. sched_barrier(0) pins each MFMA cluster
// between its barriers (rule #18). T2 XOR-swizzle + setprio kept.

typedef __attribute__((ext_vector_type(8))) __bf16 bf16x8;
typedef __attribute__((ext_vector_type(4))) float f32x4;

static constexpr float QS = 1.0f / 127.0f;

#define BAR()    asm volatile("s_barrier" ::: "memory")
#define VMCNT8() asm volatile("s_waitcnt vmcnt(8)" ::: "memory")
#define VMCNT0() asm volatile("s_waitcnt vmcnt(0)" ::: "memory")
#define LGKM8()  asm volatile("s_waitcnt lgkmcnt(8)" ::: "memory")
#define PRIO1()  __builtin_amdgcn_s_setprio(1)
#define PRIO0()  __builtin_amdgcn_s_setprio(0)
#define SB0()    __builtin_amdgcn_sched_barrier(0)

__device__ __forceinline__ void gload_lds16(const void* g, void* l) {
  __builtin_amdgcn_global_load_lds(
      (const __attribute__((address_space(1))) void*)g,
      (__attribute__((address_space(3))) void*)l,
      16, 0, 0);
}

// ---------------- conversion kernels ----------------

__global__ __launch_bounds__(256) void k_conv_x(const float* __restrict__ x,
                                                __bf16* __restrict__ xb, int n8) {
  int t = blockIdx.x * 256 + threadIdx.x;
  if (t >= n8) return;
  const float4* p = (const float4*)(x + (size_t)t * 8);
  float4 a = p[0], b = p[1];
  bf16x8 o;
  o[0] = (__bf16)a.x; o[1] = (__bf16)a.y; o[2] = (__bf16)a.z; o[3] = (__bf16)a.w;
  o[4] = (__bf16)b.x; o[5] = (__bf16)b.y; o[6] = (__bf16)b.z; o[7] = (__bf16)b.w;
  *(bf16x8*)(xb + (size_t)t * 8) = o;
}

__global__ __launch_bounds__(256) void k_conv_w1(const int* __restrict__ wg,
                                                 const int* __restrict__ wu,
                                                 __bf16* __restrict__ w1) {
  int t = blockIdx.x * 256 + threadIdx.x;
  int c8 = t & 127;
  int v = t >> 7;
  int bb = v >> 5, tt = v & 31;
  const int* src = (tt < 16) ? (wg + (size_t)(bb * 16 + tt) * 1024)
                             : (wu + (size_t)(bb * 16 + (tt & 15)) * 1024);
  const int4* p = (const int4*)(src + c8 * 8);
  int4 a = p[0], b = p[1];
  bf16x8 o;
  o[0] = (__bf16)(float)a.x; o[1] = (__bf16)(float)a.y;
  o[2] = (__bf16)(float)a.z; o[3] = (__bf16)(float)a.w;
  o[4] = (__bf16)(float)b.x; o[5] = (__bf16)(float)b.y;
  o[6] = (__bf16)(float)b.z; o[7] = (__bf16)(float)b.w;
  *(bf16x8*)(w1 + (size_t)v * 1024 + c8 * 8) = o;
}

__global__ __launch_bounds__(256) void k_conv_wd(const int* __restrict__ wdn,
                                                 __bf16* __restrict__ wdb, int n8) {
  int t = blockIdx.x * 256 + threadIdx.x;
  if (t >= n8) return;
  const int4* p = (const int4*)(wdn + (size_t)t * 8);
  int4 a = p[0], b = p[1];
  bf16x8 o;
  o[0] = (__bf16)(float)a.x; o[1] = (__bf16)(float)a.y;
  o[2] = (__bf16)(float)a.z; o[3] = (__bf16)(float)a.w;
  o[4] = (__bf16)(float)b.x; o[5] = (__bf16)(float)b.y;
  o[6] = (__bf16)(float)b.z; o[7] = (__bf16)(float)b.w;
  *(bf16x8*)(wdb + (size_t)t * 8) = o;
}

// -------- 256x256 8-phase GEMM (NT both inputs row-major [*, LDAK]) --------
// MODE 0: f32 out (*QS). MODE 1: SwiGLU bf16 out (B cols = gate|up 16-blocks).

#define MFMA16(MG, NG)                                                         \
  _Pragma("unroll") for (int mi = 0; mi < 4; ++mi) {                           \
    _Pragma("unroll") for (int nj = 0; nj < 2; ++nj) {                         \
      acc[(MG)*4 + mi][(NG)*2 + nj] = __builtin_amdgcn_mfma_f32_16x16x32_bf16( \
          af[mi][0], bf[NG][nj][0], acc[(MG)*4 + mi][(NG)*2 + nj], 0, 0, 0);   \
      acc[(MG)*4 + mi][(NG)*2 + nj] = __builtin_amdgcn_mfma_f32_16x16x32_bf16( \
          af[mi][1], bf[NG][nj][1], acc[(MG)*4 + mi][(NG)*2 + nj], 0, 0, 0);   \
    }                                                                          \
  }

#define LDAF(MG)                                                               \
  _Pragma("unroll") for (int mi = 0; mi < 4; ++mi) {                           \
    af[mi][0] = *(const bf16x8*)(aL + ((MG)*64 + mi * 16 + r16) * 128 + s0);   \
    af[mi][1] = *(const bf16x8*)(aL + ((MG)*64 + mi * 16 + r16) * 128 + s1);   \
  }

#define LDBF(NG)                                                               \
  _Pragma("unroll") for (int nj = 0; nj < 2; ++nj) {                           \
    bf[NG][nj][0] = *(const bf16x8*)(bL + (bro + (NG)*32 + nj * 16) * 128 + s0); \
    bf[NG][nj][1] = *(const bf16x8*)(bL + (bro + (NG)*32 + nj * 16) * 128 + s1); \
  }

template <int MODE, int LDAK, int NT, int LDO>
__device__ __forceinline__ void gemm8_body(const __bf16* __restrict__ A,
                                           const __bf16* __restrict__ Bp,
                                           void* __restrict__ Out,
                                           int row0, int col0, int kz) {
  __shared__ __bf16 sA[2][2][128][64];   // [buf][half][row][k]
  __shared__ __bf16 sB[2][2][128][64];
  const int tid = threadIdx.x;           // 0..511
  const int lane = tid & 63;
  const int wid = tid >> 6;              // 0..7
  const int wm = wid >> 2, wn = wid & 3; // 2 x 4 waves
  const int r16 = lane & 15;
  const int kq = lane >> 4;

  auto STG = [&](__bf16* dst, const __bf16* src, int rbase, int kt) {
    int r0 = tid >> 3;
    int c0 = (tid & 7) ^ (r0 & 7);               // inverse T2 swizzle on src
    int r1 = 64 + r0;
    gload_lds16(src + (size_t)(rbase + r0) * LDAK + kt * 64 + c0 * 8,
                dst + tid * 8);
    gload_lds16(src + (size_t)(rbase + r1) * LDAK + kt * 64 + c0 * 8,
                dst + (512 + tid) * 8);
  };

  f32x4 acc[8][4] = {};

  // prologue: T0 complete (buf0) + T1 complete (buf1); wait T0 only.
  STG(&sA[0][0][0][0], A, row0, kz);
  STG(&sA[0][1][0][0], A, row0 + 128, kz);
  STG(&sB[0][0][0][0], Bp, col0, kz);
  STG(&sB[0][1][0][0], Bp, col0 + 128, kz);
  const int kt1 = kz + (NT > 1 ? 1 : 0);
  STG(&sA[1][0][0][0], A, row0, kt1);
  STG(&sA[1][1][0][0], A, row0 + 128, kt1);
  STG(&sB[1][0][0][0], Bp, col0, kt1);
  STG(&sB[1][1][0][0], Bp, col0 + 128, kt1);
  VMCNT8();   // T0 landed; T1 (8 loads) in flight
  BAR();

  for (int t = 0; t < NT; ++t) {
    const int c = t & 1;
    const char* aL = (const char*)&sA[c][wm][0][0];
    const char* bL = (const char*)&sB[c][wn >> 1][0][0];
    const int bro = (wn & 1) * 64 + r16;
    const int s0 = ((kq) ^ (r16 & 7)) << 4;
    const int s1 = ((4 + kq) ^ (r16 & 7)) << 4;
    const int k2 = kz + (t + 2 < NT ? t + 2 : NT - 1);
    bf16x8 af[4][2], bf[2][2][2];

    // ---- phase 1: q(0,0)
    LDAF(0);
    LDBF(0);
    LGKM8();                                      // 12 reads issued; pre-drain
    BAR();
    SB0(); PRIO1(); MFMA16(0, 0); PRIO0(); SB0();
    BAR();
    // ---- phase 2: q(0,1)
    LDBF(1);
    BAR();
    SB0(); PRIO1(); MFMA16(0, 1); PRIO0(); SB0();
    BAR();
    // ---- phase 3: q(1,0)  — B regions of buf c dead (last read ph2)
    LDAF(1);
    STG(&sB[c][0][0][0], Bp, col0, k2);           // T+2 Bh0
    STG(&sB[c][1][0][0], Bp, col0 + 128, k2);     // T+2 Bh1
    BAR();
    SB0(); PRIO1(); MFMA16(1, 0); PRIO0(); SB0();
    BAR();
    // ---- phase 4: q(1,1)  — A regions of buf c dead (last read ph3)
    STG(&sA[c][0][0][0], A, row0, k2);            // T+2 Ah0
    STG(&sA[c][1][0][0], A, row0 + 128, k2);      // T+2 Ah1
    BAR();
    SB0(); PRIO1(); MFMA16(1, 1); PRIO0(); SB0();
    VMCNT8();   // 16 outstanding -> drain oldest 8 = tile T+1 complete
    BAR();
  }

  if constexpr (MODE == 1) {
    __bf16* hout = (__bf16*)Out;
    const int hbase = (col0 + wn * 64) >> 1;
#pragma unroll
    for (int i = 0; i < 8; ++i) {
#pragma unroll
      for (int p = 0; p < 2; ++p) {
#pragma unroll
        for (int rr = 0; rr < 4; ++rr) {
          int row = row0 + wm * 128 + i * 16 + kq * 4 + rr;
          float g = acc[i][2 * p][rr] * QS;
          float u = acc[i][2 * p + 1][rr] * QS;
          float hv = (g / (1.0f + __expf(-g))) * u;
          hout[(size_t)row * LDO + hbase + p * 16 + r16] = (__bf16)hv;
        }
      }
    }
  } else {
    float* out = (float*)Out;
#pragma unroll
    for (int i = 0; i < 8; ++i)
#pragma unroll
      for (int j = 0; j < 4; ++j)
#pragma unroll
        for (int rr = 0; rr < 4; ++rr) {
          int row = row0 + wm * 128 + i * 16 + kq * 4 + rr;
          int col = col0 + wn * 64 + j * 16 + r16;
          out[(size_t)row * LDO + col] = acc[i][j][rr] * QS;
        }
  }
  VMCNT0();   // drain dead tail stages before LDS handoff to next block
}

// GEMM1: [8192,1024] x [6144,1024]^T -> h [8192,3072], SwiGLU fused
__global__ __launch_bounds__(512, 2) void k_gemm1_8p(const __bf16* __restrict__ A,
                                                     const __bf16* __restrict__ B,
                                                     __bf16* __restrict__ H) {
  gemm8_body<1, 1024, 16, 3072>(A, B, H, blockIdx.y * 256, blockIdx.x * 256, 0);
}

// GEMM2: [8192,3072] x [1024,3072]^T, split-K=2 -> partials f32 [2][8192,1024]
// 256 blocks; chunked XCD swizzle: b -> w=(b&7)*32+(b>>3); w = z*128 + y*4 + x
__global__ __launch_bounds__(512, 2) void k_gemm2_8p(const __bf16* __restrict__ H,
                                                     const __bf16* __restrict__ B,
                                                     float* __restrict__ P) {
  int b = blockIdx.x;
  int w = (b & 7) * 32 + (b >> 3);
  int z = w >> 7;
  int rem = w & 127;
  int y = rem >> 2, x = rem & 3;
  gemm8_body<0, 3072, 24, 1024>(H, B, P + (size_t)z * (8192 * 1024),
                                y * 256, x * 256, z * 24);
}

// fallback (no split-K) if workspace is small
__global__ __launch_bounds__(512, 2) void k_gemm2_8p_ns(const __bf16* __restrict__ H,
                                                        const __bf16* __restrict__ B,
                                                        float* __restrict__ O) {
  gemm8_body<0, 3072, 48, 1024>(H, B, O, blockIdx.y * 256, blockIdx.x * 256, 0);
}

// out = p[z=0] + p[z=1]
__global__ __launch_bounds__(256) void k_reduce2(const float* __restrict__ p,
                                                 float* __restrict__ out, int n4) {
  int t = blockIdx.x * 256 + threadIdx.x;
  if (t >= n4) return;
  const float4* a = (const float4*)p;
  const float4* b = (const float4*)(p + (size_t)8192 * 1024);
  float4 va = a[t], vb = b[t];
  ((float4*)out)[t] = make_float4(va.x + vb.x, va.y + vb.y,
                                  va.z + vb.z, va.w + vb.w);
}

// ---------------- launch ----------------

extern "C" void kernel_launch(void* const* d_in, const int* in_sizes, int n_in,
                              void* d_out, int out_size, void* d_ws, size_t ws_size,
                              hipStream_t stream) {
  const float* x = (const float*)d_in[0];
  const int* wg = (const int*)d_in[1];
  const int* wu = (const int*)d_in[2];
  const int* wd = (const int*)d_in[3];

  char* ws = (char*)d_ws;
  __bf16* xb  = (__bf16*)(ws);                          // 16,777,216 B
  __bf16* w1  = (__bf16*)(ws + 16777216);               // 12,582,912 B
  __bf16* wdb = (__bf16*)(ws + 16777216 + 12582912);    //  6,291,456 B
  __bf16* h   = (__bf16*)(ws + 35651584);               // 50,331,648 B
  float*  part = (float*)(ws + 85983232);               // 2x 33,554,432 B
  const bool splitk = ws_size >= (size_t)85983232 + 2u * 33554432u;

  k_conv_x<<<4096, 256, 0, stream>>>(x, xb, 1048576);
  k_conv_w1<<<3072, 256, 0, stream>>>(wg, wu, w1);
  k_conv_wd<<<1536, 256, 0, stream>>>(wd, wdb, 393216);

  k_gemm1_8p<<<dim3(24, 32), 512, 0, stream>>>(xb, w1, h);

  if (splitk) {
    k_gemm2_8p<<<256, 512, 0, stream>>>(h, wdb, part);
    k_reduce2<<<8192, 256, 0, stream>>>(part, (float*)d_out, 2097152);
  } else {
    k_gemm2_8p_ns<<<dim3(4, 32), 512, 0, stream>>>(h, wdb, (float*)d_out);
  }
}

// Round 6
// 301.806 us; speedup vs baseline: 1.0459x; 1.0459x over previous
//
#include <hip/hip_runtime.h>
#include <hip/hip_bf16.h>

// SwiGLU MLP: out = (silu(x@wg^T * S) * (x@wu^T * S)) @ wd^T * S,  S = 1/127
// Round 6: break the LDS<->MFMA lockstep. Fragment ds_reads are issued ONE
// PHASE AHEAD into double register sets (afA/afB, bfA/bfB), so the LDS pipe
// fills during the previous MFMA cluster (m201's mechanism). Per iteration
// (tile t, buf c=t&1), quadrants q00,q01,q10,q11:
//   ph1: MFMA q00(afA,bfA)  | loads bf1(t)->bfB [4]   | stage Ah1(t+1)->c^1
//   ph2: MFMA q01(afA,bfB)  | loads af1(t)->afB [8]   | stage Bh0(t+2)->c
//   ph3: MFMA q10(afB,bfA)  | (no loads)              | stage Bh1(t+2)->c
//        vmcnt(4) before closing barrier  => tile t+1 fully landed
//   ph4: MFMA q11(afB,bfB)  | loads af0,bf0(t+1) [12] | stage Ah0(t+2)->c
// Region-death ledger: B(t) last read ph1 (bf1), staged-over ph2/ph3;
// A(t) last read ph2 (af1), staged-over ph4 / (t+1).ph1. Every staged half
// has >=2 full phases before first read, gated by counted vmcnt(4).
// T2 XOR-swizzle (inverse-swizzled global src, rule #21) kept; conflicts = 0.

typedef __attribute__((ext_vector_type(8))) __bf16 bf16x8;
typedef __attribute__((ext_vector_type(4))) float f32x4;

static constexpr float QS = 1.0f / 127.0f;

#define BAR()     asm volatile("s_barrier" ::: "memory")
#define VMCNT(N)  asm volatile("s_waitcnt vmcnt(" #N ")" ::: "memory")
#define PRIO1()   __builtin_amdgcn_s_setprio(1)
#define PRIO0()   __builtin_amdgcn_s_setprio(0)

__device__ __forceinline__ void gload_lds16(const void* g, void* l) {
  __builtin_amdgcn_global_load_lds(
      (const __attribute__((address_space(1))) void*)g,
      (__attribute__((address_space(3))) void*)l,
      16, 0, 0);
}

// ---------------- conversion kernels ----------------

__global__ __launch_bounds__(256) void k_conv_x(const float* __restrict__ x,
                                                __bf16* __restrict__ xb, int n8) {
  int t = blockIdx.x * 256 + threadIdx.x;
  if (t >= n8) return;
  const float4* p = (const float4*)(x + (size_t)t * 8);
  float4 a = p[0], b = p[1];
  bf16x8 o;
  o[0] = (__bf16)a.x; o[1] = (__bf16)a.y; o[2] = (__bf16)a.z; o[3] = (__bf16)a.w;
  o[4] = (__bf16)b.x; o[5] = (__bf16)b.y; o[6] = (__bf16)b.z; o[7] = (__bf16)b.w;
  *(bf16x8*)(xb + (size_t)t * 8) = o;
}

__global__ __launch_bounds__(256) void k_conv_w1(const int* __restrict__ wg,
                                                 const int* __restrict__ wu,
                                                 __bf16* __restrict__ w1) {
  int t = blockIdx.x * 256 + threadIdx.x;
  int c8 = t & 127;
  int v = t >> 7;
  int bb = v >> 5, tt = v & 31;
  const int* src = (tt < 16) ? (wg + (size_t)(bb * 16 + tt) * 1024)
                             : (wu + (size_t)(bb * 16 + (tt & 15)) * 1024);
  const int4* p = (const int4*)(src + c8 * 8);
  int4 a = p[0], b = p[1];
  bf16x8 o;
  o[0] = (__bf16)(float)a.x; o[1] = (__bf16)(float)a.y;
  o[2] = (__bf16)(float)a.z; o[3] = (__bf16)(float)a.w;
  o[4] = (__bf16)(float)b.x; o[5] = (__bf16)(float)b.y;
  o[6] = (__bf16)(float)b.z; o[7] = (__bf16)(float)b.w;
  *(bf16x8*)(w1 + (size_t)v * 1024 + c8 * 8) = o;
}

__global__ __launch_bounds__(256) void k_conv_wd(const int* __restrict__ wdn,
                                                 __bf16* __restrict__ wdb, int n8) {
  int t = blockIdx.x * 256 + threadIdx.x;
  if (t >= n8) return;
  const int4* p = (const int4*)(wdn + (size_t)t * 8);
  int4 a = p[0], b = p[1];
  bf16x8 o;
  o[0] = (__bf16)(float)a.x; o[1] = (__bf16)(float)a.y;
  o[2] = (__bf16)(float)a.z; o[3] = (__bf16)(float)a.w;
  o[4] = (__bf16)(float)b.x; o[5] = (__bf16)(float)b.y;
  o[6] = (__bf16)(float)b.z; o[7] = (__bf16)(float)b.w;
  *(bf16x8*)(wdb + (size_t)t * 8) = o;
}

// -------- 256x256 8-phase GEMM (NT both inputs row-major [*, LDAK]) --------
// MODE 0: f32 out (*QS). MODE 1: SwiGLU bf16 out (B cols = gate|up 16-blocks).

#define MFMA16(MG, NG, AF, BF)                                                 \
  _Pragma("unroll") for (int mi = 0; mi < 4; ++mi) {                           \
    _Pragma("unroll") for (int nj = 0; nj < 2; ++nj) {                         \
      acc[(MG)*4 + mi][(NG)*2 + nj] = __builtin_amdgcn_mfma_f32_16x16x32_bf16( \
          AF[mi][0], BF[nj][0], acc[(MG)*4 + mi][(NG)*2 + nj], 0, 0, 0);       \
      acc[(MG)*4 + mi][(NG)*2 + nj] = __builtin_amdgcn_mfma_f32_16x16x32_bf16( \
          AF[mi][1], BF[nj][1], acc[(MG)*4 + mi][(NG)*2 + nj], 0, 0, 0);       \
    }                                                                          \
  }

#define LDAF2(DST, MG, AL)                                                     \
  _Pragma("unroll") for (int mi = 0; mi < 4; ++mi) {                           \
    DST[mi][0] = *(const bf16x8*)((AL) + ((MG)*64 + mi * 16 + r16) * 128 + s0);\
    DST[mi][1] = *(const bf16x8*)((AL) + ((MG)*64 + mi * 16 + r16) * 128 + s1);\
  }

#define LDBF2(DST, NG, BL)                                                     \
  _Pragma("unroll") for (int nj = 0; nj < 2; ++nj) {                           \
    DST[nj][0] = *(const bf16x8*)((BL) + (bro + (NG)*32 + nj * 16) * 128 + s0);\
    DST[nj][1] = *(const bf16x8*)((BL) + (bro + (NG)*32 + nj * 16) * 128 + s1);\
  }

template <int MODE, int LDAK, int NT, int LDO>
__device__ __forceinline__ void gemm8_body(const __bf16* __restrict__ A,
                                           const __bf16* __restrict__ Bp,
                                           void* __restrict__ Out,
                                           int row0, int col0, int kz) {
  __shared__ __bf16 sA[2][2][128][64];   // [buf][half][row][k]
  __shared__ __bf16 sB[2][2][128][64];
  const int tid = threadIdx.x;           // 0..511
  const int lane = tid & 63;
  const int wid = tid >> 6;              // 0..7
  const int wm = wid >> 2, wn = wid & 3; // 2 x 4 waves
  const int r16 = lane & 15;
  const int kq = lane >> 4;
  const int bro = (wn & 1) * 64 + r16;
  const int s0 = ((kq) ^ (r16 & 7)) << 4;
  const int s1 = ((4 + kq) ^ (r16 & 7)) << 4;

  auto STG = [&](__bf16* dst, const __bf16* src, int rbase, int kt) {
    int r0 = tid >> 3;
    int c0 = (tid & 7) ^ (r0 & 7);               // inverse T2 swizzle on src
    int r1 = 64 + r0;
    gload_lds16(src + (size_t)(rbase + r0) * LDAK + kt * 64 + c0 * 8,
                dst + tid * 8);
    gload_lds16(src + (size_t)(rbase + r1) * LDAK + kt * 64 + c0 * 8,
                dst + (512 + tid) * 8);
  };

  f32x4 acc[8][4] = {};
  bf16x8 afA[4][2], afB[4][2], bfA[2][2], bfB[2][2];

  // prologue: T0 complete (8) + T1 {Bh0,Bh1,Ah0} (6); T1's Ah1 comes at t=0 ph1.
  STG(&sB[0][0][0][0], Bp, col0,       kz);
  STG(&sB[0][1][0][0], Bp, col0 + 128, kz);
  STG(&sA[0][0][0][0], A,  row0,       kz);
  STG(&sA[0][1][0][0], A,  row0 + 128, kz);
  const int kt1 = kz + (NT > 1 ? 1 : 0);
  STG(&sB[1][0][0][0], Bp, col0,       kt1);
  STG(&sB[1][1][0][0], Bp, col0 + 128, kt1);
  STG(&sA[1][0][0][0], A,  row0,       kt1);
  VMCNT(6);     // T0 landed; T1's 6 loads in flight
  BAR();
  {
    const char* aL = (const char*)&sA[0][wm][0][0];
    const char* bL = (const char*)&sB[0][wn >> 1][0][0];
    LDAF2(afA, 0, aL);   // af0(T0)
    LDBF2(bfA, 0, bL);   // bf0(T0)
  }

  for (int t = 0; t < NT; ++t) {
    const int c = t & 1;
    const char* aLc = (const char*)&sA[c][wm][0][0];
    const char* bLc = (const char*)&sB[c][wn >> 1][0][0];
    const char* aLn = (const char*)&sA[c ^ 1][wm][0][0];
    const char* bLn = (const char*)&sB[c ^ 1][wn >> 1][0][0];
    const int k1 = kz + (t + 1 < NT ? t + 1 : NT - 1);
    const int k2 = kz + (t + 2 < NT ? t + 2 : NT - 1);

    // ---- ph1: q00 | load bf1(t) | stage Ah1(t+1)
    LDBF2(bfB, 1, bLc);
    STG(&sA[c ^ 1][1][0][0], A, row0 + 128, k1);
    BAR();
    PRIO1(); MFMA16(0, 0, afA, bfA); PRIO0();
    BAR();
    // ---- ph2: q01 | load af1(t) | stage Bh0(t+2)
    LDAF2(afB, 1, aLc);
    STG(&sB[c][0][0][0], Bp, col0, k2);
    BAR();
    PRIO1(); MFMA16(0, 1, afA, bfB); PRIO0();
    BAR();
    // ---- ph3: q10 | stage Bh1(t+2) | vmcnt(4): tile t+1 fully landed
    STG(&sB[c][1][0][0], Bp, col0 + 128, k2);
    BAR();
    PRIO1(); MFMA16(1, 0, afB, bfA); PRIO0();
    VMCNT(4);
    BAR();
    // ---- ph4: q11 | load af0,bf0(t+1) from buf c^1 | stage Ah0(t+2)
    LDAF2(afA, 0, aLn);
    LDBF2(bfA, 0, bLn);
    STG(&sA[c][0][0][0], A, row0, k2);
    BAR();
    PRIO1(); MFMA16(1, 1, afB, bfB); PRIO0();
    BAR();
  }

  if constexpr (MODE == 1) {
    __bf16* hout = (__bf16*)Out;
    const int hbase = (col0 + wn * 64) >> 1;
#pragma unroll
    for (int i = 0; i < 8; ++i) {
#pragma unroll
      for (int p = 0; p < 2; ++p) {
#pragma unroll
        for (int rr = 0; rr < 4; ++rr) {
          int row = row0 + wm * 128 + i * 16 + kq * 4 + rr;
          float g = acc[i][2 * p][rr] * QS;
          float u = acc[i][2 * p + 1][rr] * QS;
          float hv = (g / (1.0f + __expf(-g))) * u;
          hout[(size_t)row * LDO + hbase + p * 16 + r16] = (__bf16)hv;
        }
      }
    }
  } else {
    float* out = (float*)Out;
#pragma unroll
    for (int i = 0; i < 8; ++i)
#pragma unroll
      for (int j = 0; j < 4; ++j)
#pragma unroll
        for (int rr = 0; rr < 4; ++rr) {
          int row = row0 + wm * 128 + i * 16 + kq * 4 + rr;
          int col = col0 + wn * 64 + j * 16 + r16;
          out[(size_t)row * LDO + col] = acc[i][j][rr] * QS;
        }
  }
  VMCNT(0);   // drain dead tail stages before LDS handoff to next block
}

// GEMM1: [8192,1024] x [6144,1024]^T -> h [8192,3072], SwiGLU fused
__global__ __launch_bounds__(512, 2) void k_gemm1_8p(const __bf16* __restrict__ A,
                                                     const __bf16* __restrict__ B,
                                                     __bf16* __restrict__ H) {
  gemm8_body<1, 1024, 16, 3072>(A, B, H, blockIdx.y * 256, blockIdx.x * 256, 0);
}

// GEMM2: [8192,3072] x [1024,3072]^T, split-K=2 -> partials f32 [2][8192,1024]
// 256 blocks; chunked XCD swizzle: b -> w=(b&7)*32+(b>>3); w = z*128 + y*4 + x
__global__ __launch_bounds__(512, 2) void k_gemm2_8p(const __bf16* __restrict__ H,
                                                     const __bf16* __restrict__ B,
                                                     float* __restrict__ P) {
  int b = blockIdx.x;
  int w = (b & 7) * 32 + (b >> 3);
  int z = w >> 7;
  int rem = w & 127;
  int y = rem >> 2, x = rem & 3;
  gemm8_body<0, 3072, 24, 1024>(H, B, P + (size_t)z * (8192 * 1024),
                                y * 256, x * 256, z * 24);
}

// fallback (no split-K) if workspace is small
__global__ __launch_bounds__(512, 2) void k_gemm2_8p_ns(const __bf16* __restrict__ H,
                                                        const __bf16* __restrict__ B,
                                                        float* __restrict__ O) {
  gemm8_body<0, 3072, 48, 1024>(H, B, O, blockIdx.y * 256, blockIdx.x * 256, 0);
}

// out = p[z=0] + p[z=1]
__global__ __launch_bounds__(256) void k_reduce2(const float* __restrict__ p,
                                                 float* __restrict__ out, int n4) {
  int t = blockIdx.x * 256 + threadIdx.x;
  if (t >= n4) return;
  const float4* a = (const float4*)p;
  const float4* b = (const float4*)(p + (size_t)8192 * 1024);
  float4 va = a[t], vb = b[t];
  ((float4*)out)[t] = make_float4(va.x + vb.x, va.y + vb.y,
                                  va.z + vb.z, va.w + vb.w);
}

// ---------------- launch ----------------

extern "C" void kernel_launch(void* const* d_in, const int* in_sizes, int n_in,
                              void* d_out, int out_size, void* d_ws, size_t ws_size,
                              hipStream_t stream) {
  const float* x = (const float*)d_in[0];
  const int* wg = (const int*)d_in[1];
  const int* wu = (const int*)d_in[2];
  const int* wd = (const int*)d_in[3];

  char* ws = (char*)d_ws;
  __bf16* xb  = (__bf16*)(ws);                          // 16,777,216 B
  __bf16* w1  = (__bf16*)(ws + 16777216);               // 12,582,912 B
  __bf16* wdb = (__bf16*)(ws + 16777216 + 12582912);    //  6,291,456 B
  __bf16* h   = (__bf16*)(ws + 35651584);               // 50,331,648 B
  float*  part = (float*)(ws + 85983232);               // 2x 33,554,432 B
  const bool splitk = ws_size >= (size_t)85983232 + 2u * 33554432u;

  k_conv_x<<<4096, 256, 0, stream>>>(x, xb, 1048576);
  k_conv_w1<<<3072, 256, 0, stream>>>(wg, wu, w1);
  k_conv_wd<<<1536, 256, 0, stream>>>(wd, wdb, 393216);

  k_gemm1_8p<<<dim3(24, 32), 512, 0, stream>>>(xb, w1, h);

  if (splitk) {
    k_gemm2_8p<<<256, 512, 0, stream>>>(h, wdb, part);
    k_reduce2<<<8192, 256, 0, stream>>>(part, (float*)d_out, 2097152);
  } else {
    k_gemm2_8p_ns<<<dim3(4, 32), 512, 0, stream>>>(h, wdb, (float*)d_out);
  }
}